// Round 2
// baseline (86.094 us; speedup 1.0000x reference)
//
#include <hip/hip_runtime.h>

#define DEVINL __device__ __forceinline__

namespace {

constexpr int NB   = 4;
constexpr int CINv = 512;
constexpr int HIDv = 64;
constexpr int NCl  = 11;   // NC+1 output channels
constexpr int h1v = 60, w1v = 80;
constexpr int h2v = 30, w2v = 40;
constexpr int Hf = 480, Wf = 640;
constexpr int PPB1 = h1v * w1v;     // 4800 coarse px / batch
constexpr int PPB2 = h2v * w2v;     // 1200
constexpr int NP1 = NB * PPB1;      // 19200
constexpr int NP2 = NB * PPB2;      // 4800
constexpr int PPBF = Hf * Wf;       // 307200 fine px / batch
constexpr int NPF = NB * PPBF;      // 1228800

// workspace layout (float elements)
constexpr size_t WS_P1  = 0;                               // 2*64*19200 partials conv1
constexpr size_t WS_P2  = WS_P1 + 2ull * HIDv * NP1;       // 2*64*4800 partials conv2
constexpr size_t WS_Z   = WS_P2 + 2ull * HIDv * NP2;       // 4*11*4800 coarse logits
constexpr size_t WS_BBX = WS_Z + (size_t)NB * NCl * PPB1;  // 36*5 ints

// output layout (float elements)
constexpr size_t OUT_SEG = (size_t)NB * NCl * PPBF;  // 13,516,800
constexpr size_t OUT_BBX = OUT_SEG + (size_t)NPF;    // +1,228,800

DEVINL int iclamp(int v, int lo, int hi) { return v < lo ? lo : (v > hi ? hi : v); }

// ---------------------------------------------------------------------------
// Kernel 1: both 1x1 convs as K-split GEMM partials.
// Tile: 64 pixels x 64 outputs, K-half = 256 (8 chunks of 32).
// Thread: 4 px x 4 out accumulators.  Grid: 600 (conv1) + 150 (conv2).
// ---------------------------------------------------------------------------
template <int PPB>
DEVINL void gemm_tile(const float* __restrict__ F, const float* __restrict__ Wt,
                      float* __restrict__ P, int npix, int tile, int khalf,
                      float* A_lds /*[32][64]*/, float* W_lds /*[32][68]*/) {
  const int t = threadIdx.x;
  const int pg = t & 15;       // pixel group (4 px)
  const int og = t >> 4;       // output group (4 outs)
  const int gp0 = tile * 64;
  const int c0 = khalf * 256;

  float acc[4][4];
#pragma unroll
  for (int i = 0; i < 4; ++i)
#pragma unroll
    for (int j = 0; j < 4; ++j) acc[i][j] = 0.f;

  for (int kb = 0; kb < 8; ++kb) {
    const int cb = c0 + kb * 32;
    __syncthreads();
    // stage A chunk: A_lds[cc][px] (stride 64), coalesced global reads
#pragma unroll
    for (int e = 0; e < 8; ++e) {
      int idx = e * 256 + t;
      int cc = idx >> 6, px = idx & 63;
      int gp = gp0 + px;
      int b = gp / PPB, pb = gp % PPB;   // compile-time PPB -> magic mul
      A_lds[idx] = F[((size_t)b * CINv + (cb + cc)) * PPB + pb];
    }
    // stage W chunk: W_lds[cc][o] (stride 68, pad kills write bank conflicts)
#pragma unroll
    for (int e = 0; e < 8; ++e) {
      int idx = e * 256 + t;
      int o = idx >> 5, cc = idx & 31;
      W_lds[cc * 68 + o] = Wt[o * CINv + cb + cc];
    }
    __syncthreads();
#pragma unroll
    for (int cc = 0; cc < 32; ++cc) {
      float4 a = *reinterpret_cast<const float4*>(&A_lds[cc * 64 + pg * 4]);
      float4 w = *reinterpret_cast<const float4*>(&W_lds[cc * 68 + og * 4]);
      float av[4] = {a.x, a.y, a.z, a.w};
      float wv[4] = {w.x, w.y, w.z, w.w};
#pragma unroll
      for (int i = 0; i < 4; ++i)
#pragma unroll
        for (int j = 0; j < 4; ++j)
          acc[i][j] = fmaf(av[i], wv[j], acc[i][j]);
    }
  }
  // write partials: P[(khalf*64 + o) * npix + gpix], float4 over px
#pragma unroll
  for (int j = 0; j < 4; ++j) {
    int o = og * 4 + j;
    float4 v;
    v.x = acc[0][j]; v.y = acc[1][j]; v.z = acc[2][j]; v.w = acc[3][j];
    *reinterpret_cast<float4*>(&P[((size_t)khalf * HIDv + o) * npix + gp0 + pg * 4]) = v;
  }
}

__global__ __launch_bounds__(256) void k_gemm(const float* __restrict__ f1,
                                              const float* __restrict__ f2,
                                              const float* __restrict__ w1,
                                              const float* __restrict__ w2,
                                              float* __restrict__ ws) {
  __shared__ float A_lds[32 * 64];
  __shared__ float W_lds[32 * 68];
  const int bid = blockIdx.x;

  // init bbx accumulators once per launch (deterministic, runs before k_up_softmax)
  if (bid == 0 && threadIdx.x < 180) {
    int f = threadIdx.x % 5;
    int v = (f == 0) ? 0 : ((f == 1 || f == 3) ? 0x7fffffff : (int)0x80000000);
    reinterpret_cast<int*>(ws + WS_BBX)[threadIdx.x] = v;
  }

  if (bid < 600) {
    gemm_tile<PPB1>(f1, w1, ws + WS_P1, NP1, bid >> 1, bid & 1, A_lds, W_lds);
  } else {
    int tt = bid - 600;
    gemm_tile<PPB2>(f2, w2, ws + WS_P2, NP2, tt >> 1, tt & 1, A_lds, W_lds);
  }
}

// ---------------------------------------------------------------------------
// Kernel 2: combine partials -> relu+bias, add x2-upsampled branch2 (recomputed
// from partials), then 64->11 GEMM per pixel -> z (coarse logits).
// Grid: 300 blocks x 256 thr; 64 px per block; thread = (px, channel-quarter).
// ---------------------------------------------------------------------------
__global__ __launch_bounds__(256) void k_combine_z(const float* __restrict__ ws_ro,
                                                   float* __restrict__ ws,
                                                   const float* __restrict__ b1,
                                                   const float* __restrict__ b2,
                                                   const float* __restrict__ w3,
                                                   const float* __restrict__ b3) {
  __shared__ float inter[64 * 64];  // [ch][px]
  const int t = threadIdx.x;
  const int pxl = t & 63;
  const int qi = t >> 6;  // 0..3
  const int gp = blockIdx.x * 64 + pxl;
  const int b = gp / PPB1, pb = gp % PPB1;
  const int y = pb / w1v, x = pb % w1v;

  // x2 bilinear (half-pixel, edge clamp)
  const float sx = x * 0.5f - 0.25f;
  const float x0f = floorf(sx);
  const float fx = sx - x0f;
  const int ix0 = iclamp((int)x0f, 0, w2v - 1);
  const int ix1 = iclamp((int)x0f + 1, 0, w2v - 1);
  const float sy = y * 0.5f - 0.25f;
  const float y0f = floorf(sy);
  const float fy = sy - y0f;
  const int iy0 = iclamp((int)y0f, 0, h2v - 1);
  const int iy1 = iclamp((int)y0f + 1, 0, h2v - 1);

  const float* p1 = ws_ro + WS_P1;
  const float* p2 = ws_ro + WS_P2;
  const int base2 = b * PPB2;
  const int i00 = base2 + iy0 * w2v + ix0;
  const int i01 = base2 + iy0 * w2v + ix1;
  const int i10 = base2 + iy1 * w2v + ix0;
  const int i11 = base2 + iy1 * w2v + ix1;

#pragma unroll
  for (int cc = 0; cc < 16; ++cc) {
    const int ch = qi * 16 + cc;
    float v = p1[(size_t)ch * NP1 + gp] + p1[(size_t)(HIDv + ch) * NP1 + gp] + b1[ch];
    v = fmaxf(v, 0.f);
    const float* pa = p2 + (size_t)ch * NP2;
    const float* pbp = p2 + (size_t)(HIDv + ch) * NP2;
    const float bb = b2[ch];
    float v00 = fmaxf(pa[i00] + pbp[i00] + bb, 0.f);
    float v01 = fmaxf(pa[i01] + pbp[i01] + bb, 0.f);
    float v10 = fmaxf(pa[i10] + pbp[i10] + bb, 0.f);
    float v11 = fmaxf(pa[i11] + pbp[i11] + bb, 0.f);
    float top = v00 + fx * (v01 - v00);
    float bot = v10 + fx * (v11 - v10);
    v += top + fy * (bot - top);
    inter[ch * 64 + pxl] = v;
  }
  __syncthreads();

  // z = W3 * inter + b3, groups {0-2}{3-5}{6-8}{9-10}
  const int o0 = qi * 3;
  const int ocnt = (qi == 3) ? 2 : 3;
  float* z = ws + WS_Z;
  for (int oo = 0; oo < ocnt; ++oo) {
    const int o = o0 + oo;
    float acc = b3[o];
#pragma unroll
    for (int ch = 0; ch < 64; ++ch)
      acc = fmaf(inter[ch * 64 + pxl], w3[o * HIDv + ch], acc);
    z[((size_t)b * NCl + o) * PPB1 + pb] = acc;
  }
}

// ---------------------------------------------------------------------------
// Kernel 3: x8 bilinear of z + relu + softmax + argmax + bbx accumulation.
// v2: LDS-staged z tile. Block = 128x8 fine-pixel tile (1200 blocks x 256thr),
// 4 px/thread along x. Coarse footprint 11ch x 3rows x 18cols staged once,
// all bilinear taps then come from LDS (kills the 44 scalar global loads /
// thread that made v1 latency-bound at 19% occupancy / 18% VALUBusy).
// ---------------------------------------------------------------------------
__global__ __launch_bounds__(256) void k_up_softmax(const float* __restrict__ ws,
                                                    float* __restrict__ out,
                                                    int* __restrict__ bbxAcc) {
  constexpr int ZR = 3, ZC = 18, ZN = NCl * ZR * ZC;  // 594
  __shared__ float zt[ZN];
  __shared__ int sCnt[10], sXmin[10], sXmax[10], sYmin[10], sYmax[10];

  const int t = threadIdx.x;
  const int tile = blockIdx.x;
  const int tx = tile % 5;            // x-tile (128 px each)
  const int ty = (tile / 5) % 60;     // y-tile (8 rows each)
  const int b  = tile / 300;

  const int base_x = tx * 16 - 1;     // coarse col of zt col 0 (may be -1)
  const int base_y = ty - 1;          // coarse row of zt row 0 (may be -1)

  if (t < 10) {
    sCnt[t] = 0;
    sXmin[t] = 0x7fffffff; sXmax[t] = (int)0x80000000;
    sYmin[t] = 0x7fffffff; sYmax[t] = (int)0x80000000;
  }
  // stage z tile (edge-clamped)
  const float* zb = ws + WS_Z + (size_t)b * NCl * PPB1;
  for (int e = t; e < ZN; e += 256) {
    int ch = e / (ZR * ZC);
    int rc = e % (ZR * ZC);
    int row = rc / ZC, col = rc % ZC;
    int gr = iclamp(base_y + row, 0, h1v - 1);
    int gc = iclamp(base_x + col, 0, w1v - 1);
    zt[e] = zb[(size_t)ch * PPB1 + gr * w1v + gc];
  }
  __syncthreads();

  const int xg = t & 31;              // 4-px group within the 128-wide tile
  const int yr = t >> 5;              // row 0..7 within tile
  const int X = tx * 128 + xg * 4;
  const int Y = ty * 8 + yr;
  const int r = Y * Wf + X;

  // all 4 px in a 4-aligned group share floor(sx); likewise the row shares
  // floor(sy). Local tap indices into zt:
  const int lcx0 = (xg + 1) >> 1;          // 0..16
  const int lry0 = (yr >= 4) ? 1 : 0;      // 0..1
  const float fy = (Y + 0.5f) * 0.125f - 0.5f - (float)(base_y + lry0);
  float fxk[4];
#pragma unroll
  for (int k = 0; k < 4; ++k)
    fxk[k] = (X + k + 0.5f) * 0.125f - 0.5f - (float)(base_x + lcx0);

  float lg[NCl][4];
#pragma unroll
  for (int c = 0; c < NCl; ++c) {
    const int base = c * (ZR * ZC) + lry0 * ZC + lcx0;
    float v00 = zt[base],       v01 = zt[base + 1];
    float v10 = zt[base + ZC],  v11 = zt[base + ZC + 1];
    float l0 = v00 + fy * (v10 - v00);
    float l1 = v01 + fy * (v11 - v01);
#pragma unroll
    for (int k = 0; k < 4; ++k)
      lg[c][k] = fmaxf(l0 + fxk[k] * (l1 - l0), 0.f);  // relu(logit)
  }

  // argmax over logits (== argmax over softmax probs, same first-index ties),
  // then softmax with max-subtraction.
  int bestc[4];
#pragma unroll
  for (int k = 0; k < 4; ++k) {
    float m = lg[0][k];
    int bi = 0;
#pragma unroll
    for (int c = 1; c < NCl; ++c) {
      if (lg[c][k] > m) { m = lg[c][k]; bi = c; }
    }
    bestc[k] = bi;
    float s = 0.f;
#pragma unroll
    for (int c = 0; c < NCl; ++c) {
      float e = __expf(lg[c][k] - m);
      lg[c][k] = e;
      s += e;
    }
    const float inv = __builtin_amdgcn_rcpf(s);
#pragma unroll
    for (int c = 0; c < NCl; ++c) lg[c][k] *= inv;
  }

  // probability stores (float4 per channel; each wave = >=512B segments)
  float* prob = out + (size_t)b * NCl * PPBF;
#pragma unroll
  for (int c = 0; c < NCl; ++c) {
    float4 v;
    v.x = lg[c][0]; v.y = lg[c][1]; v.z = lg[c][2]; v.w = lg[c][3];
    *reinterpret_cast<float4*>(&prob[(size_t)c * PPBF + r]) = v;
  }
  // segmentation store
  {
    float4 v;
    v.x = (float)bestc[0]; v.y = (float)bestc[1];
    v.z = (float)bestc[2]; v.w = (float)bestc[3];
    *reinterpret_cast<float4*>(&out[OUT_SEG + (size_t)b * PPBF + r]) = v;
  }

  // bbx: per-thread combine then LDS atomics (classes 1..9 only)
  for (int c = 1; c <= 9; ++c) {
    int cnt = 0, mnx = 0x7fffffff, mxx = (int)0x80000000;
#pragma unroll
    for (int k = 0; k < 4; ++k)
      if (bestc[k] == c) { ++cnt; mnx = min(mnx, X + k); mxx = max(mxx, X + k); }
    if (cnt) {
      atomicAdd(&sCnt[c], cnt);
      atomicMin(&sXmin[c], mnx);
      atomicMax(&sXmax[c], mxx);
      atomicMin(&sYmin[c], Y);
      atomicMax(&sYmax[c], Y);
    }
  }
  __syncthreads();
  if (t >= 1 && t <= 9 && sCnt[t] > 0) {
    int* e = bbxAcc + (b * 9 + (t - 1)) * 5;
    atomicAdd(e + 0, sCnt[t]);
    atomicMin(e + 1, sXmin[t]);
    atomicMax(e + 2, sXmax[t]);
    atomicMin(e + 3, sYmin[t]);
    atomicMax(e + 4, sYmax[t]);
  }
}

// ---------------------------------------------------------------------------
// Kernel 4: finalize bbx rows (36 x 6), THRESH = 100.
// ---------------------------------------------------------------------------
__global__ void k_bbx_final(const int* __restrict__ acc, float* __restrict__ out) {
  const int t = threadIdx.x;
  if (t >= 36) return;
  const int* e = acc + t * 5;
  float* o = out + OUT_BBX + t * 6;
  if (e[0] >= 100) {
    o[0] = (float)(t / 9);
    o[1] = (float)e[1];  // xmin
    o[2] = (float)e[3];  // ymin
    o[3] = (float)e[2];  // xmax
    o[4] = (float)e[4];  // ymax
    o[5] = (float)(t % 9 + 1);
  } else {
    for (int i = 0; i < 6; ++i) o[i] = -1.f;
  }
}

}  // namespace

extern "C" void kernel_launch(void* const* d_in, const int* in_sizes, int n_in,
                              void* d_out, int out_size, void* d_ws, size_t ws_size,
                              hipStream_t stream) {
  const float* f1 = (const float*)d_in[0];
  const float* f2 = (const float*)d_in[1];
  const float* w1 = (const float*)d_in[2];
  const float* b1 = (const float*)d_in[3];
  const float* w2 = (const float*)d_in[4];
  const float* b2 = (const float*)d_in[5];
  const float* w3 = (const float*)d_in[6];
  const float* b3 = (const float*)d_in[7];
  float* out = (float*)d_out;
  float* ws = (float*)d_ws;

  hipLaunchKernelGGL(k_gemm, dim3(750), dim3(256), 0, stream, f1, f2, w1, w2, ws);
  hipLaunchKernelGGL(k_combine_z, dim3(300), dim3(256), 0, stream, ws, ws, b1, b2, w3, b3);
  hipLaunchKernelGGL(k_up_softmax, dim3(1200), dim3(256), 0, stream, ws, out,
                     (int*)(ws + WS_BBX));
  hipLaunchKernelGGL(k_bbx_final, dim3(1), dim3(64), 0, stream,
                     (const int*)(ws + WS_BBX), out);
}

// Round 3
// 69.480 us; speedup vs baseline: 1.2391x; 1.2391x over previous
//
#include <hip/hip_runtime.h>

#define DEVINL __device__ __forceinline__

namespace {

constexpr int NB   = 4;
constexpr int CINv = 512;
constexpr int HIDv = 64;
constexpr int NCl  = 11;   // NC+1 output channels
constexpr int h1v = 60, w1v = 80;
constexpr int h2v = 30, w2v = 40;
constexpr int Hf = 480, Wf = 640;
constexpr int PPB1 = h1v * w1v;     // 4800 coarse px / batch
constexpr int PPB2 = h2v * w2v;     // 1200
constexpr int NP1 = NB * PPB1;      // 19200
constexpr int NP2 = NB * PPB2;      // 4800
constexpr int PPBF = Hf * Wf;       // 307200 fine px / batch
constexpr int NPF = NB * PPBF;      // 1228800

// workspace layout (float elements)
constexpr size_t WS_P1  = 0;                               // 2*64*19200 partials conv1
constexpr size_t WS_P2  = WS_P1 + 2ull * HIDv * NP1;       // 2*64*4800 partials conv2
constexpr size_t WS_Z   = WS_P2 + 2ull * HIDv * NP2;       // 4*11*4800 coarse logits
constexpr size_t WS_BBX = WS_Z + (size_t)NB * NCl * PPB1;  // 36 entries x 32 ints (128B pad)

// output layout (float elements)
constexpr size_t OUT_SEG = (size_t)NB * NCl * PPBF;  // 13,516,800
constexpr size_t OUT_BBX = OUT_SEG + (size_t)NPF;    // +1,228,800

DEVINL int iclamp(int v, int lo, int hi) { return v < lo ? lo : (v > hi ? hi : v); }

// ---------------------------------------------------------------------------
// Kernel 1: both 1x1 convs as K-split GEMM partials.
// Tile: 64 pixels x 64 outputs, K-half = 256 (8 chunks of 32).
// Thread: 4 px x 4 out accumulators.  Grid: 600 (conv1) + 150 (conv2).
// ---------------------------------------------------------------------------
template <int PPB>
DEVINL void gemm_tile(const float* __restrict__ F, const float* __restrict__ Wt,
                      float* __restrict__ P, int npix, int tile, int khalf,
                      float* A_lds /*[32][64]*/, float* W_lds /*[32][68]*/) {
  const int t = threadIdx.x;
  const int pg = t & 15;       // pixel group (4 px)
  const int og = t >> 4;       // output group (4 outs)
  const int gp0 = tile * 64;
  const int c0 = khalf * 256;

  float acc[4][4];
#pragma unroll
  for (int i = 0; i < 4; ++i)
#pragma unroll
    for (int j = 0; j < 4; ++j) acc[i][j] = 0.f;

  for (int kb = 0; kb < 8; ++kb) {
    const int cb = c0 + kb * 32;
    __syncthreads();
    // stage A chunk: A_lds[cc][px] (stride 64), coalesced global reads
#pragma unroll
    for (int e = 0; e < 8; ++e) {
      int idx = e * 256 + t;
      int cc = idx >> 6, px = idx & 63;
      int gp = gp0 + px;
      int b = gp / PPB, pb = gp % PPB;   // compile-time PPB -> magic mul
      A_lds[idx] = F[((size_t)b * CINv + (cb + cc)) * PPB + pb];
    }
    // stage W chunk: W_lds[cc][o] (stride 68, pad kills write bank conflicts)
#pragma unroll
    for (int e = 0; e < 8; ++e) {
      int idx = e * 256 + t;
      int o = idx >> 5, cc = idx & 31;
      W_lds[cc * 68 + o] = Wt[o * CINv + cb + cc];
    }
    __syncthreads();
#pragma unroll
    for (int cc = 0; cc < 32; ++cc) {
      float4 a = *reinterpret_cast<const float4*>(&A_lds[cc * 64 + pg * 4]);
      float4 w = *reinterpret_cast<const float4*>(&W_lds[cc * 68 + og * 4]);
      float av[4] = {a.x, a.y, a.z, a.w};
      float wv[4] = {w.x, w.y, w.z, w.w};
#pragma unroll
      for (int i = 0; i < 4; ++i)
#pragma unroll
        for (int j = 0; j < 4; ++j)
          acc[i][j] = fmaf(av[i], wv[j], acc[i][j]);
    }
  }
  // write partials: P[(khalf*64 + o) * npix + gpix], float4 over px
#pragma unroll
  for (int j = 0; j < 4; ++j) {
    int o = og * 4 + j;
    float4 v;
    v.x = acc[0][j]; v.y = acc[1][j]; v.z = acc[2][j]; v.w = acc[3][j];
    *reinterpret_cast<float4*>(&P[((size_t)khalf * HIDv + o) * npix + gp0 + pg * 4]) = v;
  }
}

__global__ __launch_bounds__(256) void k_gemm(const float* __restrict__ f1,
                                              const float* __restrict__ f2,
                                              const float* __restrict__ w1,
                                              const float* __restrict__ w2,
                                              float* __restrict__ ws) {
  __shared__ float A_lds[32 * 64];
  __shared__ float W_lds[32 * 68];
  const int bid = blockIdx.x;

  // init bbx accumulators once per launch (runs before k_bbx)
  if (bid == 0 && threadIdx.x < 180) {
    int entry = threadIdx.x / 5, f = threadIdx.x % 5;
    int v = (f == 0) ? 0 : ((f == 1 || f == 3) ? 0x7fffffff : (int)0x80000000);
    reinterpret_cast<int*>(ws + WS_BBX)[entry * 32 + f] = v;
  }

  if (bid < 600) {
    gemm_tile<PPB1>(f1, w1, ws + WS_P1, NP1, bid >> 1, bid & 1, A_lds, W_lds);
  } else {
    int tt = bid - 600;
    gemm_tile<PPB2>(f2, w2, ws + WS_P2, NP2, tt >> 1, tt & 1, A_lds, W_lds);
  }
}

// ---------------------------------------------------------------------------
// Kernel 2: combine partials -> relu+bias, add x2-upsampled branch2 (recomputed
// from partials), then 64->11 GEMM per pixel -> z (coarse logits).
// Grid: 300 blocks x 256 thr; 64 px per block; thread = (px, channel-quarter).
// ---------------------------------------------------------------------------
__global__ __launch_bounds__(256) void k_combine_z(const float* __restrict__ ws_ro,
                                                   float* __restrict__ ws,
                                                   const float* __restrict__ b1,
                                                   const float* __restrict__ b2,
                                                   const float* __restrict__ w3,
                                                   const float* __restrict__ b3) {
  __shared__ float inter[64 * 64];  // [ch][px]
  const int t = threadIdx.x;
  const int pxl = t & 63;
  const int qi = t >> 6;  // 0..3
  const int gp = blockIdx.x * 64 + pxl;
  const int b = gp / PPB1, pb = gp % PPB1;
  const int y = pb / w1v, x = pb % w1v;

  // x2 bilinear (half-pixel, edge clamp)
  const float sx = x * 0.5f - 0.25f;
  const float x0f = floorf(sx);
  const float fx = sx - x0f;
  const int ix0 = iclamp((int)x0f, 0, w2v - 1);
  const int ix1 = iclamp((int)x0f + 1, 0, w2v - 1);
  const float sy = y * 0.5f - 0.25f;
  const float y0f = floorf(sy);
  const float fy = sy - y0f;
  const int iy0 = iclamp((int)y0f, 0, h2v - 1);
  const int iy1 = iclamp((int)y0f + 1, 0, h2v - 1);

  const float* p1 = ws_ro + WS_P1;
  const float* p2 = ws_ro + WS_P2;
  const int base2 = b * PPB2;
  const int i00 = base2 + iy0 * w2v + ix0;
  const int i01 = base2 + iy0 * w2v + ix1;
  const int i10 = base2 + iy1 * w2v + ix0;
  const int i11 = base2 + iy1 * w2v + ix1;

#pragma unroll
  for (int cc = 0; cc < 16; ++cc) {
    const int ch = qi * 16 + cc;
    float v = p1[(size_t)ch * NP1 + gp] + p1[(size_t)(HIDv + ch) * NP1 + gp] + b1[ch];
    v = fmaxf(v, 0.f);
    const float* pa = p2 + (size_t)ch * NP2;
    const float* pbp = p2 + (size_t)(HIDv + ch) * NP2;
    const float bb = b2[ch];
    float v00 = fmaxf(pa[i00] + pbp[i00] + bb, 0.f);
    float v01 = fmaxf(pa[i01] + pbp[i01] + bb, 0.f);
    float v10 = fmaxf(pa[i10] + pbp[i10] + bb, 0.f);
    float v11 = fmaxf(pa[i11] + pbp[i11] + bb, 0.f);
    float top = v00 + fx * (v01 - v00);
    float bot = v10 + fx * (v11 - v10);
    v += top + fy * (bot - top);
    inter[ch * 64 + pxl] = v;
  }
  __syncthreads();

  // z = W3 * inter + b3, groups {0-2}{3-5}{6-8}{9-10}
  const int o0 = qi * 3;
  const int ocnt = (qi == 3) ? 2 : 3;
  float* z = ws + WS_Z;
  for (int oo = 0; oo < ocnt; ++oo) {
    const int o = o0 + oo;
    float acc = b3[o];
#pragma unroll
    for (int ch = 0; ch < 64; ++ch)
      acc = fmaf(inter[ch * 64 + pxl], w3[o * HIDv + ch], acc);
    z[((size_t)b * NCl + o) * PPB1 + pb] = acc;
  }
}

// ---------------------------------------------------------------------------
// Kernel 3: x8 bilinear of z + relu + softmax + argmax.  v3: 1 px/thread so
// lg[11] stays in registers (no remat/spill), bbx moved to its own pass.
// Block = 128x2 fine tile, grid 4800 (= 5 x 240 x 4), ~18 waves/SIMD.
// ---------------------------------------------------------------------------
__global__ __launch_bounds__(256) void k_up_softmax(const float* __restrict__ ws,
                                                    float* __restrict__ out) {
  constexpr int ZR = 3, ZC = 18, ZN = NCl * ZR * ZC;  // 594
  __shared__ float zt[ZN];
  const int t = threadIdx.x;
  const int tile = blockIdx.x;
  const int tx = tile % 5;
  const int ty = (tile / 5) % 240;
  const int b  = tile / 1200;
  const int base_x = tx * 16 - 1;
  const int row0 = ty * 2;
  const int base_y = (int)floorf((row0 + 0.5f) * 0.125f - 0.5f);

  // stage z tile (edge-clamped)
  const float* zb = ws + WS_Z + (size_t)b * NCl * PPB1;
  for (int e = t; e < ZN; e += 256) {
    int ch = e / (ZR * ZC);
    int rc = e % (ZR * ZC);
    int row = rc / ZC, col = rc % ZC;
    int gr = iclamp(base_y + row, 0, h1v - 1);
    int gc = iclamp(base_x + col, 0, w1v - 1);
    zt[e] = zb[(size_t)ch * PPB1 + gr * w1v + gc];
  }
  __syncthreads();

  const int x  = t & 127;
  const int rr = t >> 7;
  const int X = tx * 128 + x;
  const int Y = row0 + rr;

  const float sy = (Y + 0.5f) * 0.125f - 0.5f;
  const int y0g = (int)floorf(sy);
  const float fy = sy - (float)y0g;
  const int lry = y0g - base_y;                       // 0 or 1
  const int lcx = (2 * x + 9) >> 4;                   // 0..16
  const float fx = (float)(2 * x - 7) * 0.0625f + 1.0f - (float)lcx;

  float lg[NCl];
  float m = -1.f;
  int bi = 0;
#pragma unroll
  for (int c = 0; c < NCl; ++c) {
    const int base = c * (ZR * ZC) + lry * ZC + lcx;
    float v00 = zt[base],      v01 = zt[base + 1];
    float v10 = zt[base + ZC], v11 = zt[base + ZC + 1];
    float l0 = v00 + fy * (v10 - v00);
    float l1 = v01 + fy * (v11 - v01);
    float v = fmaxf(l0 + fx * (l1 - l0), 0.f);        // relu(logit)
    lg[c] = v;
    if (v > m) { m = v; bi = c; }                     // first-index tiebreak
  }

  float s = 0.f;
#pragma unroll
  for (int c = 0; c < NCl; ++c) {
    float e = __expf(lg[c] - m);
    lg[c] = e;
    s += e;
  }
  const float inv = __builtin_amdgcn_rcpf(s);

  const size_t r = (size_t)Y * Wf + X;
  float* prob = out + (size_t)b * NCl * PPBF;
#pragma unroll
  for (int c = 0; c < NCl; ++c)
    prob[(size_t)c * PPBF + r] = lg[c] * inv;
  out[OUT_SEG + (size_t)b * PPBF + r] = (float)bi;
}

// ---------------------------------------------------------------------------
// Kernel 3b: bbx from seg via wave-ballot (no per-pixel atomics).
// Grid 480 x 256: block = (batch, 4 rows); wave = 1 row; 10 chunks of 64 px.
// Lanes map to contiguous x -> ballot+popc+ctz/clz give count/xmin/xmax.
// ---------------------------------------------------------------------------
__global__ __launch_bounds__(256) void k_bbx(const float* __restrict__ seg,
                                             int* __restrict__ acc) {
  __shared__ int sC[10], sXn[10], sXx[10], sYn[10], sYx[10];
  const int t = threadIdx.x;
  const int lane = t & 63, w = t >> 6;
  const int b = blockIdx.x / 120;
  const int rg = blockIdx.x % 120;
  const int row = rg * 4 + w;
  if (t < 10) {
    sC[t] = 0;
    sXn[t] = 0x7fffffff; sXx[t] = (int)0x80000000;
    sYn[t] = 0x7fffffff; sYx[t] = (int)0x80000000;
  }
  __syncthreads();

  int cnt[10], xmn[10], xmx[10];
#pragma unroll
  for (int c = 1; c <= 9; ++c) { cnt[c] = 0; xmn[c] = 0x7fffffff; xmx[c] = -1; }

  const float* srow = seg + (size_t)b * PPBF + (size_t)row * Wf;
  for (int ch = 0; ch < 10; ++ch) {
    const int cls = (int)srow[ch * 64 + lane];
#pragma unroll
    for (int c = 1; c <= 9; ++c) {
      unsigned long long msk = __ballot(cls == c);
      if (msk) {  // wave-uniform branch
        cnt[c] += (int)__popcll(msk);
        xmn[c] = min(xmn[c], ch * 64 + (int)__builtin_ctzll(msk));
        xmx[c] = max(xmx[c], ch * 64 + 63 - (int)__builtin_clzll(msk));
      }
    }
  }

  if (lane == 0) {
#pragma unroll
    for (int c = 1; c <= 9; ++c) {
      if (cnt[c]) {
        atomicAdd(&sC[c], cnt[c]);
        atomicMin(&sXn[c], xmn[c]);
        atomicMax(&sXx[c], xmx[c]);
        atomicMin(&sYn[c], row);
        atomicMax(&sYx[c], row);
      }
    }
  }
  __syncthreads();
  if (t >= 1 && t <= 9 && sC[t] > 0) {
    int* e = acc + (b * 9 + (t - 1)) * 32;   // 128B-padded entries
    atomicAdd(e + 0, sC[t]);
    atomicMin(e + 1, sXn[t]);
    atomicMax(e + 2, sXx[t]);
    atomicMin(e + 3, sYn[t]);
    atomicMax(e + 4, sYx[t]);
  }
}

// ---------------------------------------------------------------------------
// Kernel 4: finalize bbx rows (36 x 6), THRESH = 100.
// ---------------------------------------------------------------------------
__global__ void k_bbx_final(const int* __restrict__ acc, float* __restrict__ out) {
  const int t = threadIdx.x;
  if (t >= 36) return;
  const int* e = acc + t * 32;
  float* o = out + OUT_BBX + t * 6;
  if (e[0] >= 100) {
    o[0] = (float)(t / 9);
    o[1] = (float)e[1];  // xmin
    o[2] = (float)e[3];  // ymin
    o[3] = (float)e[2];  // xmax
    o[4] = (float)e[4];  // ymax
    o[5] = (float)(t % 9 + 1);
  } else {
    for (int i = 0; i < 6; ++i) o[i] = -1.f;
  }
}

}  // namespace

extern "C" void kernel_launch(void* const* d_in, const int* in_sizes, int n_in,
                              void* d_out, int out_size, void* d_ws, size_t ws_size,
                              hipStream_t stream) {
  const float* f1 = (const float*)d_in[0];
  const float* f2 = (const float*)d_in[1];
  const float* w1 = (const float*)d_in[2];
  const float* b1 = (const float*)d_in[3];
  const float* w2 = (const float*)d_in[4];
  const float* b2 = (const float*)d_in[5];
  const float* w3 = (const float*)d_in[6];
  const float* b3 = (const float*)d_in[7];
  float* out = (float*)d_out;
  float* ws = (float*)d_ws;

  hipLaunchKernelGGL(k_gemm, dim3(750), dim3(256), 0, stream, f1, f2, w1, w2, ws);
  hipLaunchKernelGGL(k_combine_z, dim3(300), dim3(256), 0, stream, ws, ws, b1, b2, w3, b3);
  hipLaunchKernelGGL(k_up_softmax, dim3(4800), dim3(256), 0, stream, ws, out);
  hipLaunchKernelGGL(k_bbx, dim3(480), dim3(256), 0, stream, out + OUT_SEG,
                     (int*)(ws + WS_BBX));
  hipLaunchKernelGGL(k_bbx_final, dim3(1), dim3(64), 0, stream,
                     (const int*)(ws + WS_BBX), out);
}